// Round 3
// baseline (16296.983 us; speedup 1.0000x reference)
//
#include <hip/hip_runtime.h>
#include <hip/hip_bf16.h>
#include <math.h>

#define BATCH 4
#define SEQ   2048
#define DIM   1024
#define MROWS (SEQ*BATCH)          // 8192
#define BIGN  ((size_t)MROWS*DIM)  // 8388608 floats per buffer

// ---------------- chunked scan for r_t = dec*r + k*v,  ret = q*r --------------
// 64 chunks of 32 steps. Phase A: per-chunk end value with r0=0.
__global__ __launch_bounds__(256) void scan_a(const float* __restrict__ K,
    const float* __restrict__ V, const float* __restrict__ dec_p,
    float* __restrict__ E)
{
  int id  = blockIdx.x*256 + threadIdx.x;   // 0..262143
  int c   = id >> 12;
  int rem = id & 4095;
  int b   = rem >> 10;
  int dc  = rem & 1023;
  float dec = dec_p[dc >> 6];
  size_t base = ((size_t)b*SEQ + (size_t)c*32)*DIM + dc;
  float r = 0.f;
  #pragma unroll 4
  for (int i = 0; i < 32; ++i) {
    float kv = K[base + (size_t)i*DIM] * V[base + (size_t)i*DIM];
    r = fmaf(dec, r, kv);
  }
  E[(size_t)c*4096 + rem] = r;
}

// Phase B: serial prefix over the 64 chunk end-values -> carry into each chunk.
__global__ __launch_bounds__(256) void scan_b(const float* __restrict__ E,
    const float* __restrict__ dec_p, float* __restrict__ carry)
{
  int id = blockIdx.x*256 + threadIdx.x;    // 0..4095
  int dc = id & 1023;
  float dec = dec_p[dc >> 6];
  float d2 = dec*dec, d4 = d2*d2, d8 = d4*d4, d16 = d8*d8, d32 = d16*d16;
  float r = 0.f;
  #pragma unroll 1
  for (int c = 0; c < 64; ++c) {
    carry[(size_t)c*4096 + id] = r;
    r = fmaf(d32, r, E[(size_t)c*4096 + id]);
  }
}

// Phase C: replay chunk with true carry; write retained = q*r in [t*4+b][d] layout.
__global__ __launch_bounds__(256) void scan_c(const float* __restrict__ Q,
    const float* __restrict__ K, const float* __restrict__ V,
    const float* __restrict__ dec_p, const float* __restrict__ carry,
    float* __restrict__ ret)
{
  int id  = blockIdx.x*256 + threadIdx.x;
  int c   = id >> 12;
  int rem = id & 4095;
  int b   = rem >> 10;
  int dc  = rem & 1023;
  float dec = dec_p[dc >> 6];
  size_t base = ((size_t)b*SEQ + (size_t)c*32)*DIM + dc;
  float r = carry[(size_t)c*4096 + rem];
  #pragma unroll 1
  for (int i = 0; i < 32; ++i) {
    int t = c*32 + i;
    float kv = K[base + (size_t)i*DIM] * V[base + (size_t)i*DIM];
    r = fmaf(dec, r, kv);
    ret[((size_t)t*BATCH + b)*DIM + dc] = Q[base + (size_t)i*DIM] * r;
  }
}

// ---------------- fp32 tiled GEMM: C[m,n] = sum_k X[m,k]*W[n,k] (+bias) -------
// MODE 0: C = XW^T + bias
// MODE 1: g = sigmoid(XW^T + bias) -> C;  u_out = (1-g)*inp
// MODE 2: C += XW^T
// MODE 3: outf[b,t,n] = XW^T + bias   (m = t*4+b scatter), float32 output
// MODE 4: C = XW^T
#define GM 64
#define GN 64
#define GK 32
#define LDA 68

template<int MODE>
__global__ __launch_bounds__(256) void gemm_k(
    const float* __restrict__ X, const float* __restrict__ W,
    const float* __restrict__ bias, float* __restrict__ C,
    const float* __restrict__ inp, float* __restrict__ u_out,
    float* __restrict__ outf)
{
  __shared__ float Xs[GK][LDA];
  __shared__ float Ws[GK][LDA];
  const int tid = threadIdx.x;
  const int m0 = blockIdx.y * GM;
  const int n0 = blockIdx.x * GN;
  const int tx = tid & 15, ty = tid >> 4;
  float acc[4][4] = {};
  #pragma unroll 1
  for (int kb = 0; kb < DIM; kb += GK) {
    #pragma unroll
    for (int h = 0; h < 2; ++h) {
      int idx = tid + h*256;
      int row = idx >> 3;        // 0..63
      int kc  = (idx & 7) << 2;  // 0,4,...,28
      float4 xv = *(const float4*)(X + (size_t)(m0+row)*DIM + kb + kc);
      Xs[kc+0][row] = xv.x; Xs[kc+1][row] = xv.y;
      Xs[kc+2][row] = xv.z; Xs[kc+3][row] = xv.w;
      float4 wv = *(const float4*)(W + (size_t)(n0+row)*DIM + kb + kc);
      Ws[kc+0][row] = wv.x; Ws[kc+1][row] = wv.y;
      Ws[kc+2][row] = wv.z; Ws[kc+3][row] = wv.w;
    }
    __syncthreads();
    #pragma unroll
    for (int kk = 0; kk < GK; ++kk) {
      float4 a = *(const float4*)&Xs[kk][ty << 2];
      float4 w = *(const float4*)&Ws[kk][tx << 2];
      float av[4] = {a.x, a.y, a.z, a.w};
      float wv[4] = {w.x, w.y, w.z, w.w};
      #pragma unroll
      for (int i = 0; i < 4; ++i)
        #pragma unroll
        for (int j = 0; j < 4; ++j)
          acc[i][j] = fmaf(av[i], wv[j], acc[i][j]);
    }
    __syncthreads();
  }
  float bj[4];
  #pragma unroll
  for (int j = 0; j < 4; ++j)
    bj[j] = (MODE == 0 || MODE == 1 || MODE == 3) ? bias[n0 + (tx<<2) + j] : 0.f;
  #pragma unroll
  for (int i = 0; i < 4; ++i) {
    int m = m0 + (ty<<2) + i;
    #pragma unroll
    for (int j = 0; j < 4; ++j) {
      int n = n0 + (tx<<2) + j;
      size_t off = (size_t)m*DIM + n;
      float vv = acc[i][j] + bj[j];
      if (MODE == 2) vv += C[off];
      if (MODE == 1) {
        float gv = 1.f/(1.f + expf(-vv));
        C[off] = gv;
        u_out[off] = (1.f - gv) * inp[off];
      } else if (MODE == 3) {
        // m = t*4+b  ->  out[b][t][n], float32
        outf[((size_t)(m & 3)*SEQ + (size_t)(m >> 2))*DIM + n] = vv;
      } else {
        C[off] = vv;
      }
    }
  }
}

// ---------------- sequential recurrence: s_t = tanh((g_t*s_{t-1})@A^T + d_t) --
#define RG  32     // workgroups; each owns RR rows of A
#define RR  32
#define ALD 1028   // padded row stride in floats (breaks bank-conflict stride)

__global__ __launch_bounds__(256) void recur_k(
    const float* __restrict__ A, const float* __restrict__ g,
    const float* __restrict__ dpre, float* __restrict__ s,
    int* __restrict__ ctr)
{
  __shared__ float  As[RR][ALD];    // 131584 B
  __shared__ float4 xs[4][257];     // 16448 B
  __shared__ float  red[4][4][RR];  // 2048 B
  const int tid  = threadIdx.x;
  const int base = blockIdx.x * RR;
  for (int idx = tid; idx < RR*DIM/4; idx += 256) {
    int r = idx >> 8;            // 0..31
    int c = (idx & 255) << 2;    // 0..1020
    float4 av = *(const float4*)(A + (size_t)(base + r)*DIM + c);
    As[r][c+0] = av.x; As[r][c+1] = av.y; As[r][c+2] = av.z; As[r][c+3] = av.w;
  }
  const int wv = tid >> 6;       // wave -> k-quarter
  const int ln = tid & 63;
  const int b  = ln & 3;
  const int r0 = ln >> 2;        // rows r0 and r0+16
  __syncthreads();

  #pragma unroll 1
  for (int t = 0; t < SEQ; ++t) {
    if (t == 0) {
      float4 z = make_float4(0.f,0.f,0.f,0.f);
      for (int i = tid; i < 1024; i += 256) xs[i >> 8][i & 255] = z;
    } else {
      if (tid == 0) {
        int guard = 0;
        while (__hip_atomic_load(ctr + t - 1, __ATOMIC_RELAXED,
                                 __HIP_MEMORY_SCOPE_AGENT) < RG) {
          if (++guard > (1 << 27)) break;   // anti-hang bailout
        }
      }
      __syncthreads();
      __builtin_amdgcn_fence(__ATOMIC_ACQUIRE, "agent");   // every wave
      const float4* gp = (const float4*)(g + (size_t)t*BATCH*DIM);
      const float4* sp = (const float4*)(s + (size_t)(t-1)*BATCH*DIM);
      for (int i = tid; i < 1024; i += 256) {
        float4 gv = gp[i], sv = sp[i], xv;
        xv.x = gv.x*sv.x; xv.y = gv.y*sv.y; xv.z = gv.z*sv.z; xv.w = gv.w*sv.w;
        xs[i >> 8][i & 255] = xv;
      }
    }
    __syncthreads();
    float acc0 = 0.f, acc1 = 0.f;
    const float4* xr = &xs[b][wv*64];
    const float4* a0 = (const float4*)&As[r0][wv*256];
    const float4* a1 = (const float4*)&As[r0+16][wv*256];
    #pragma unroll 8
    for (int i = 0; i < 64; ++i) {
      float4 xv = xr[i], av = a0[i], bv = a1[i];
      acc0 = fmaf(xv.x,av.x, fmaf(xv.y,av.y, fmaf(xv.z,av.z, fmaf(xv.w,av.w, acc0))));
      acc1 = fmaf(xv.x,bv.x, fmaf(xv.y,bv.y, fmaf(xv.z,bv.z, fmaf(xv.w,bv.w, acc1))));
    }
    red[wv][b][r0]      = acc0;
    red[wv][b][r0+16]   = acc1;
    __syncthreads();
    if (tid < 128) {
      int bb = tid >> 5;
      int rr = tid & 31;
      float sum = red[0][bb][rr] + red[1][bb][rr] + red[2][bb][rr] + red[3][bb][rr];
      size_t off = ((size_t)t*BATCH + bb)*DIM + base + rr;
      s[off] = tanhf(sum + dpre[off]);
    }
    __syncthreads();   // vmcnt(0) drain of the s-stores before publishing
    if (tid == 0) {
      __builtin_amdgcn_fence(__ATOMIC_RELEASE, "agent");
      atomicAdd(ctr + t, 1);
    }
  }
}

// ------------------------------------------------------------------------------
extern "C" void kernel_launch(void* const* d_in, const int* in_sizes, int n_in,
                              void* d_out, int out_size, void* d_ws, size_t ws_size,
                              hipStream_t stream)
{
  (void)in_sizes; (void)n_in; (void)out_size;
  const float* q   = (const float*)d_in[0];
  const float* k   = (const float*)d_in[1];
  const float* v   = (const float*)d_in[2];
  const float* Wi  = (const float*)d_in[3];
  const float* bi  = (const float*)d_in[4];
  const float* Wg  = (const float*)d_in[5];
  const float* bg  = (const float*)d_in[6];
  const float* A   = (const float*)d_in[7];
  const float* Bm  = (const float*)d_in[8];
  const float* Wo  = (const float*)d_in[9];
  const float* bo  = (const float*)d_in[10];
  const float* dec = (const float*)d_in[11];

  size_t need = (4*BIGN + 2*(size_t)64*4096)*sizeof(float) + SEQ*sizeof(int);
  if (ws_size < need) return;

  float* b0 = (float*)d_ws;          // ret -> u -> s
  float* b1 = b0 + BIGN;             // inp
  float* b2 = b1 + BIGN;             // g
  float* b3 = b2 + BIGN;             // d  (pre-activation constant)
  float* E     = b3 + BIGN;
  float* carry = E + (size_t)64*4096;
  int*   ctr   = (int*)(carry + (size_t)64*4096);
  float* outp  = (float*)d_out;

  hipMemsetAsync(ctr, 0, SEQ*sizeof(int), stream);

  scan_a<<<1024, 256, 0, stream>>>(k, v, dec, E);
  scan_b<<<16,   256, 0, stream>>>(E, dec, carry);
  scan_c<<<1024, 256, 0, stream>>>(q, k, v, dec, carry, b0);

  dim3 gg(DIM/GN, MROWS/GM);
  gemm_k<0><<<gg, 256, 0, stream>>>(b0, Wi, bi, b1, nullptr, nullptr, nullptr); // inp
  gemm_k<1><<<gg, 256, 0, stream>>>(b1, Wg, bg, b2, b1, b0, nullptr);           // g, u
  gemm_k<4><<<gg, 256, 0, stream>>>(b0, A,  nullptr, b3, nullptr, nullptr, nullptr); // d  = u@A^T
  gemm_k<2><<<gg, 256, 0, stream>>>(b1, Bm, nullptr, b3, nullptr, nullptr, nullptr); // d += inp@Bm^T

  recur_k<<<RG, 256, 0, stream>>>(A, b2, b3, b0, ctr);                          // s

  gemm_k<3><<<gg, 256, 0, stream>>>(b0, Wo, bo, nullptr, nullptr, nullptr, outp); // out
}